// Round 1
// baseline (368.256 us; speedup 1.0000x reference)
//
#include <hip/hip_runtime.h>

// FeatureFuser: out = sigmoid(select(sampling_map, refined[k] last-window-wins))
// B=8, TOP_K=4, C=32, H=256, W=256, GRID_SIZE=4 -> grid_h=grid_w=64, window=192
//
// Layout facts used:
//   float4 index within one [C,H,W] map: idx4 = c*16384 + h*64 + w4   (2^19 per b)
//   sampling idx4  = b*2^19 + (c*16384 + h*64 + w4)   == global idx4
//   refined  idx4  = idx4 + (3*b + k) * 2^19
//   Window x bounds are multiples of 64 floats -> every float4 is fully in/out.

#define TOPK 4
#define GRID_H 64
#define WIN 192

__global__ __launch_bounds__(256) void FeatureFuser_kernel(
    const float* __restrict__ samp,
    const float* __restrict__ refined,
    const int*   __restrict__ regions,
    float*       __restrict__ out)
{
    const int idx4 = blockIdx.x * 256 + threadIdx.x;   // float4 index, < 2^22
    const int w = (idx4 & 63) << 2;        // 0..255 (float column of first elem)
    const int h = (idx4 >> 6) & 255;       // 0..255
    const int b = idx4 >> 19;              // 0..7  (wave-uniform)

    // --- detect int64 vs int32 storage of the 64-value region table ---
    // int64-LE signature: every odd 32-bit word is zero. Wave-uniform s_loads.
    bool i64 = true;
    #pragma unroll
    for (int i = 0; i < 32; ++i) i64 &= (regions[2 * i + 1] == 0);
    const int stride = i64 ? 2 : 1;

    // --- branchless last-window-wins selection ---
    int src_k = -1;
    #pragma unroll
    for (int k = 0; k < TOPK; ++k) {
        const int base = ((b * TOPK + k) * 2) * stride;
        const int y0 = regions[base] * GRID_H;
        const int x0 = regions[base + stride] * GRID_H;
        // y_end = min(y0+192, 256) but h < 256 always, so h < y0+192 suffices
        const bool in = (h >= y0) & (h < y0 + WIN) & (w >= x0) & (w < x0 + WIN);
        if (in) src_k = k;   // ascending k: last write wins (matches reference)
    }

    const float4* __restrict__ sp =
        (src_k < 0) ? (const float4*)samp : (const float4*)refined;
    const int off4 = (src_k < 0) ? idx4 : idx4 + ((3 * b + src_k) << 19);

    float4 v = sp[off4];

    v.x = 1.0f / (1.0f + __expf(-v.x));
    v.y = 1.0f / (1.0f + __expf(-v.y));
    v.z = 1.0f / (1.0f + __expf(-v.z));
    v.w = 1.0f / (1.0f + __expf(-v.w));

    ((float4*)out)[idx4] = v;
}

extern "C" void kernel_launch(void* const* d_in, const int* in_sizes, int n_in,
                              void* d_out, int out_size, void* d_ws, size_t ws_size,
                              hipStream_t stream)
{
    const float* samp    = (const float*)d_in[0];   // [8,32,256,256] f32
    const float* refined = (const float*)d_in[1];   // [8,4,32,256,256] f32
    const int*   regions = (const int*)d_in[2];     // [8,4,2] int32 (or int64, auto-detected)
    float*       out     = (float*)d_out;           // [8,32,256,256] f32

    const int total4 = out_size >> 2;               // 4,194,304 float4s
    const int blocks = total4 / 256;                // 16384
    FeatureFuser_kernel<<<blocks, 256, 0, stream>>>(samp, refined, regions, out);
}

// Round 2
// 357.722 us; speedup vs baseline: 1.0294x; 1.0294x over previous
//
#include <hip/hip_runtime.h>

// FeatureFuser: out = sigmoid(select(sampling_map, refined[k] last-window-wins))
// B=8, TOP_K=4, C=32, H=256, W=256, GRID_SIZE=4 -> grid_h=grid_w=64, window=192
//
// Layout facts:
//   float4 index within one [C,H,W] map: local4 = c*16384 + h*64 + w4 (2^19 per b)
//   sampling idx4 = (b<<19) | local4
//   refined  idx4 = idx4 + (3*b + k) << 19
//   Window x bounds are multiples of 64 floats -> every float4 fully in/out.
//
// Round 1 change: region table handled ONCE by a 1-wave prep kernel into d_ws;
// main kernel uses b = blockIdx.y so bounds loads are wave-uniform (s_load),
// removing ~40 per-thread cached vector loads + waits.

#define TOPK 4
#define GRID_H 64
#define WIN 192

// Prep: detect int64 vs int32 storage, write y0/x0 (in pixels) per (b,k).
// ws layout: ws[(b*TOPK + k)*2 + 0] = y0, +1 = x0   (64 ints, 256 B)
__global__ void FeatureFuser_prep(const int* __restrict__ regions,
                                  int* __restrict__ ws)
{
    if (threadIdx.x == 0) {
        // int64-LE signature: every odd 32-bit word of the 64-value table is 0.
        // Values are in [0,4), so for true int32 data P(all zero) ~ 4^-32.
        bool i64 = true;
        for (int i = 0; i < 32; ++i) i64 = i64 && (regions[2 * i + 1] == 0);
        const int stride = i64 ? 2 : 1;
        for (int i = 0; i < 32; ++i) {
            ws[2 * i]     = regions[(2 * i)     * stride] * GRID_H;  // y0
            ws[2 * i + 1] = regions[(2 * i + 1) * stride] * GRID_H;  // x0
        }
    }
}

__global__ __launch_bounds__(256) void FeatureFuser_kernel(
    const float* __restrict__ samp,
    const float* __restrict__ refined,
    const int*   __restrict__ bounds,   // precomputed in d_ws
    float*       __restrict__ out)
{
    const int b      = blockIdx.y;                     // wave-uniform
    const int local4 = blockIdx.x * 256 + threadIdx.x; // < 2^19
    const int idx4   = (b << 19) | local4;

    const int w = (local4 & 63) << 2;      // float column of first elem, 0..255
    const int h = (local4 >> 6) & 255;     // 0..255

    // Wave-uniform bounds -> scalar loads
    int src_k = -1;
    #pragma unroll
    for (int k = 0; k < TOPK; ++k) {
        const int y0 = bounds[(b * TOPK + k) * 2];
        const int x0 = bounds[(b * TOPK + k) * 2 + 1];
        const bool in = (h >= y0) & (h < y0 + WIN) & (w >= x0) & (w < x0 + WIN);
        if (in) src_k = k;   // ascending k: last write wins
    }

    const float4* __restrict__ sp =
        (src_k < 0) ? (const float4*)samp : (const float4*)refined;
    const int off4 = (src_k < 0) ? idx4 : idx4 + ((3 * b + src_k) << 19);

    float4 v = sp[off4];

    v.x = 1.0f / (1.0f + __expf(-v.x));
    v.y = 1.0f / (1.0f + __expf(-v.y));
    v.z = 1.0f / (1.0f + __expf(-v.z));
    v.w = 1.0f / (1.0f + __expf(-v.w));

    ((float4*)out)[idx4] = v;
}

extern "C" void kernel_launch(void* const* d_in, const int* in_sizes, int n_in,
                              void* d_out, int out_size, void* d_ws, size_t ws_size,
                              hipStream_t stream)
{
    const float* samp    = (const float*)d_in[0];   // [8,32,256,256] f32
    const float* refined = (const float*)d_in[1];   // [8,4,32,256,256] f32
    const int*   regions = (const int*)d_in[2];     // [8,4,2] int32 or int64
    float*       out     = (float*)d_out;           // [8,32,256,256] f32
    int*         ws      = (int*)d_ws;

    FeatureFuser_prep<<<1, 64, 0, stream>>>(regions, ws);

    // per-b float4 count: 32*256*256/4 = 524288 -> 2048 blocks of 256
    dim3 grid(2048, 8);
    FeatureFuser_kernel<<<grid, 256, 0, stream>>>(samp, refined, ws, out);
}

// Round 4
// 347.536 us; speedup vs baseline: 1.0596x; 1.0293x over previous
//
#include <hip/hip_runtime.h>

// FeatureFuser: out = sigmoid(select(sampling_map, refined[k] last-window-wins))
// B=8, TOP_K=4, C=32, H=256, W=256, GRID_SIZE=4 -> grid_h=grid_w=64, window=192
//
// Layout facts:
//   float4 index within one [C,H,W] map: local4 = c*16384 + h*64 + w4 (2^19 per b)
//   sampling idx4 = (b<<19) | local4
//   refined  idx4 = idx4 + (3*b + k) << 19
//   Window x bounds are multiples of 64 floats -> every float4 fully in/out.
//
// Round 3 fix: __builtin_nontemporal_* requires a native vector type, not
// HIP_vector_type -> use ext_vector_type(4) float alias.

#define TOPK 4
#define GRID_H 64
#define WIN 192

typedef float f32x4 __attribute__((ext_vector_type(4)));

__global__ __launch_bounds__(256) void FeatureFuser_kernel(
    const float* __restrict__ samp,
    const float* __restrict__ refined,
    const int*   __restrict__ regions,
    float*       __restrict__ out)
{
    const int b      = blockIdx.y;                     // wave-uniform
    const int local4 = blockIdx.x * 256 + threadIdx.x; // < 2^19
    const int idx4   = (b << 19) | local4;

    const int w = (local4 & 63) << 2;      // float column of first elem, 0..255
    const int h = (local4 >> 6) & 255;     // 0..255

    // --- wave-uniform region decode (scalar loads, L2-hit) ---
    // int64-LE signature: every odd 32-bit word of the 64-value table is 0.
    // Values in [0,4), so for genuine int32 data P(all zero) ~ 4^-32.
    bool i64 = true;
    #pragma unroll
    for (int i = 0; i < 32; ++i) i64 &= (regions[2 * i + 1] == 0);
    const int stride = i64 ? 2 : 1;

    // --- branchless last-window-wins selection ---
    int src_k = -1;
    #pragma unroll
    for (int k = 0; k < TOPK; ++k) {
        const int base = ((b * TOPK + k) * 2) * stride;
        const int y0 = regions[base] * GRID_H;
        const int x0 = regions[base + stride] * GRID_H;
        const bool in = (h >= y0) & (h < y0 + WIN) & (w >= x0) & (w < x0 + WIN);
        if (in) src_k = k;   // ascending k: last write wins
    }

    const f32x4* __restrict__ sp =
        (src_k < 0) ? (const f32x4*)samp : (const f32x4*)refined;
    const int off4 = (src_k < 0) ? idx4 : idx4 + ((3 * b + src_k) << 19);

    f32x4 v = __builtin_nontemporal_load(sp + off4);

    v.x = 1.0f / (1.0f + __expf(-v.x));
    v.y = 1.0f / (1.0f + __expf(-v.y));
    v.z = 1.0f / (1.0f + __expf(-v.z));
    v.w = 1.0f / (1.0f + __expf(-v.w));

    __builtin_nontemporal_store(v, ((f32x4*)out) + idx4);
}

extern "C" void kernel_launch(void* const* d_in, const int* in_sizes, int n_in,
                              void* d_out, int out_size, void* d_ws, size_t ws_size,
                              hipStream_t stream)
{
    const float* samp    = (const float*)d_in[0];   // [8,32,256,256] f32
    const float* refined = (const float*)d_in[1];   // [8,4,32,256,256] f32
    const int*   regions = (const int*)d_in[2];     // [8,4,2] int32 or int64
    float*       out     = (float*)d_out;           // [8,32,256,256] f32

    // per-b float4 count: 32*256*256/4 = 524288 -> 2048 blocks of 256
    dim3 grid(2048, 8);
    FeatureFuser_kernel<<<grid, 256, 0, stream>>>(samp, refined, regions, out);
}